// Round 12
// baseline (634.655 us; speedup 1.0000x reference)
//
#include <hip/hip_runtime.h>
#include <math.h>

#define N_NODES 16000
#define N_EDGES 128000
#define KDIM 1024
#define N_RELS 7
#define NB_GOS 4096
#define KCAT (KDIM * (N_RELS + 1))     // 8192: [feat | agg r0..r6]
#define MPAD 16128                     // 63 * 256

#define BM 128
#define BN 128
#define BK 32
#define CAP2 (N_EDGES + N_RELS * BM)   // fallback path
#define NTILE_E (CAP2 / BM)

typedef __attribute__((ext_vector_type(8))) short bf16x8;
typedef __attribute__((ext_vector_type(8))) unsigned short u16x8;
typedef __attribute__((ext_vector_type(4))) float f32x4;

__device__ __forceinline__ unsigned short f2bf(float f) {
    union { float f; unsigned int u; } v; v.f = f;
    unsigned int u = v.u + 0x7FFFu + ((v.u >> 16) & 1u);   // RNE
    return (unsigned short)(u >> 16);
}

__device__ __forceinline__ float bf2f(unsigned short u) {
    union { unsigned int u; float f; } v; v.u = (unsigned int)u << 16;
    return v.f;
}

__device__ __forceinline__ void gload16(const void* g, void* lds) {
    __builtin_amdgcn_global_load_lds(
        (const __attribute__((address_space(1))) unsigned int*)g,
        (__attribute__((address_space(3))) unsigned int*)lds, 16, 0, 0);
}

// ---------------- prep kernels ----------------

__global__ __launch_bounds__(256) void conv_bf16(const float* __restrict__ in,
                                                 unsigned short* __restrict__ out, int n8) {
    int i = blockIdx.x * 256 + threadIdx.x;
    if (i >= n8) return;
    const float4* in4 = (const float4*)in;
    float4 x = in4[2 * i], y = in4[2 * i + 1];
    u16x8 o;
    o[0] = f2bf(x.x); o[1] = f2bf(x.y); o[2] = f2bf(x.z); o[3] = f2bf(x.w);
    o[4] = f2bf(y.x); o[5] = f2bf(y.y); o[6] = f2bf(y.z); o[7] = f2bf(y.w);
    *(u16x8*)&out[(size_t)i * 8] = o;
}

__global__ __launch_bounds__(256) void conv_cat(const float* __restrict__ in,
                                                unsigned short* __restrict__ Acat) {
    int i = blockIdx.x * 256 + threadIdx.x;
    if (i >= N_NODES * (KDIM / 8)) return;
    int n = i >> 7, c8 = (i & 127) * 8;
    const float4* in4 = (const float4*)(in + (size_t)n * KDIM + c8);
    float4 x = in4[0], y = in4[1];
    u16x8 o;
    o[0] = f2bf(x.x); o[1] = f2bf(x.y); o[2] = f2bf(x.z); o[3] = f2bf(x.w);
    o[4] = f2bf(y.x); o[5] = f2bf(y.y); o[6] = f2bf(y.z); o[7] = f2bf(y.w);
    *(u16x8*)&Acat[(size_t)n * KCAT + c8] = o;
}

__global__ void transpose_w(const float* __restrict__ Wrel,
                            const float* __restrict__ Wloop,
                            unsigned short* __restrict__ WrelT,
                            unsigned short* __restrict__ WloopT) {
    __shared__ float t[32][33];
    int z = blockIdx.z;
    const float* src = (z < N_RELS) ? Wrel + (size_t)z * KDIM * KDIM : Wloop;
    unsigned short* dst = (z < N_RELS) ? WrelT + (size_t)z * KDIM * KDIM : WloopT;
    int tx = threadIdx.x, ty = threadIdx.y;
    int x = blockIdx.x * 32 + tx;
    int y0 = blockIdx.y * 32;
    #pragma unroll
    for (int j = 0; j < 4; j++)
        t[ty + 8 * j][tx] = src[(size_t)(y0 + ty + 8 * j) * KDIM + x];
    __syncthreads();
    #pragma unroll
    for (int j = 0; j < 4; j++) {
        int n = blockIdx.x * 32 + ty + 8 * j;
        dst[(size_t)n * KDIM + y0 + tx] = f2bf(t[tx][ty + 8 * j]);
    }
}

__global__ void transpose_cat(const float* __restrict__ Wrel,
                              const float* __restrict__ Wloop,
                              unsigned short* __restrict__ BT) {
    __shared__ float t[32][33];
    int z = blockIdx.z;
    const float* src = (z == 0) ? Wloop : Wrel + (size_t)(z - 1) * KDIM * KDIM;
    int tx = threadIdx.x, ty = threadIdx.y;
    int x = blockIdx.x * 32 + tx;
    int y0 = blockIdx.y * 32;
    #pragma unroll
    for (int j = 0; j < 4; j++)
        t[ty + 8 * j][tx] = src[(size_t)(y0 + ty + 8 * j) * KDIM + x];
    __syncthreads();
    #pragma unroll
    for (int j = 0; j < 4; j++) {
        int o = blockIdx.x * 32 + ty + 8 * j;
        BT[(size_t)o * KCAT + z * KDIM + y0 + tx] = f2bf(t[tx][ty + 8 * j]);
    }
}

// ---------------- dst-sort + aggregation (fast path) ----------------

__global__ void zero_ints(int* p, int n) {
    int i = blockIdx.x * 256 + threadIdx.x;
    if (i < n) p[i] = 0;
}

__global__ void hist_dst(const int* __restrict__ dst, int* cnt) {
    int e = blockIdx.x * 256 + threadIdx.x;
    if (e < N_EDGES) atomicAdd(&cnt[dst[e]], 1);
}

__global__ __launch_bounds__(1024) void scan_offs(const int* __restrict__ cnt,
                                                  int* __restrict__ offs) {
    __shared__ int part[1024];
    int t = threadIdx.x;
    int base = t * 16;
    int local[16];
    int s = 0;
    if (base < N_NODES) {
        #pragma unroll
        for (int j = 0; j < 16; j++) { local[j] = cnt[base + j]; s += local[j]; }
    }
    part[t] = s;
    __syncthreads();
    for (int d = 1; d < 1024; d <<= 1) {
        int v = (t >= d) ? part[t - d] : 0;
        __syncthreads();
        part[t] += v;
        __syncthreads();
    }
    if (base < N_NODES) {
        int ex = (t == 0) ? 0 : part[t - 1];
        #pragma unroll
        for (int j = 0; j < 16; j++) { offs[base + j] = ex; ex += local[j]; }
        if (base + 16 == N_NODES) offs[N_NODES] = ex;
    }
}

__global__ void scatter_dst(const int* __restrict__ src, const int* __restrict__ dst,
                            const int* __restrict__ et, const int* __restrict__ offs,
                            int* cursor, int* __restrict__ se) {
    int e = blockIdx.x * 256 + threadIdx.x;
    if (e < N_EDGES) {
        int d = dst[e];
        int p = atomicAdd(&cursor[d], 1);
        se[offs[d] + p] = (src[e] << 3) | et[e];
    }
}

// per-node aggregation: reads src rows in BF16 from Acat's feat region,
// fp32 accumulate, bf16 store. (r10 win: halves read bytes vs fp32 feat.)
__global__ __launch_bounds__(256) void aggregate(const int* __restrict__ offs,
                                                 const int* __restrict__ se,
                                                 unsigned short* __restrict__ Acat) {
    int n = blockIdx.x;
    int t = threadIdx.x;
    int e0 = offs[n], e1 = offs[n + 1];
    float4 a0 = {0,0,0,0}, a1 = a0, a2 = a0, a3 = a0, a4 = a0, a5 = a0, a6 = a0;
    for (int i = e0; i < e1; i++) {
        int v = se[i];                      // wave-uniform
        int s = v >> 3, r = v & 7;
        ushort4 q = *(const ushort4*)&Acat[(size_t)s * KCAT + t * 4];
        float4 x = { bf2f(q.x), bf2f(q.y), bf2f(q.z), bf2f(q.w) };
        #define ADD4(a) { a.x += x.x; a.y += x.y; a.z += x.z; a.w += x.w; }
        switch (r) {                        // uniform branch (same edge blockwide)
            case 0: ADD4(a0) break; case 1: ADD4(a1) break;
            case 2: ADD4(a2) break; case 3: ADD4(a3) break;
            case 4: ADD4(a4) break; case 5: ADD4(a5) break;
            default: ADD4(a6) break;
        }
        #undef ADD4
    }
    unsigned short* row = Acat + (size_t)n * KCAT + KDIM;
    #define ST4(rr, a) { ushort4 o; o.x = f2bf(a.x); o.y = f2bf(a.y); \
                         o.z = f2bf(a.z); o.w = f2bf(a.w); \
                         *(ushort4*)(row + rr * KDIM + t * 4) = o; }
    ST4(0, a0) ST4(1, a1) ST4(2, a2) ST4(3, a3) ST4(4, a4) ST4(5, a5) ST4(6, a6)
    #undef ST4
}

// ======== 256x256 GEMM, BK=64, 2 K-tiles/iter, read<->MFMA interleaved =======
// MODE 0: hb = bf16(A @ BT^T + bias)        MODE 2: out = sigmoid(... + |rad|)
// vs r11: within each phase, A-frag ds_reads are interleaved with the MFMA
// octets (per mi: {2 ds_read_b128 -> 8 MFMA}) instead of bunching all 16
// reads ahead of a 32-MFMA cluster. The compiler's fine-grained lgkmcnt then
// lets MFMA(mi) start after only its own operands, hiding the later reads
// under earlier MFMA and letting the 2 waves/SIMD offset their read/MFMA
// bursts (r11's serial-sum phase: reads_all_waves + MFMA_all_waves).
// A-pair is transient (8 VGPR) vs afr[4][2] (32) -> frees ~24 VGPR.
// Barrier / stage / counted-vmcnt ledger byte-identical to r10/r11
// (twice validated; stage-target halves disjoint from in-phase reads).
//  P1: LDB->b0,b1; stage Ahi,Bhi(2t+1)->buf1; {LDA2,8MFMA}x4 (MH0) | bar
//  P2: stage Alo,Blo(2t+2)->buf0; {LDA2,8MFMA}x4 (MH1) | vmcnt(4) | bar
//  P3: LDB->b0,b1; stage Ahi,Bhi(2t+2)->buf0; {LDA2,8MFMA}x4 (MH0) | bar
//  P4: stage Alo,Blo(2t+3)->buf1; {LDA2,8MFMA}x4 (MH1) | vmcnt(4) | bar

template<int MODE, int KD>
__global__ __launch_bounds__(512, 2) void gemm256(
    const unsigned short* __restrict__ A,    // [Mpad][KD] bf16
    const unsigned short* __restrict__ BT,   // [N][KD] bf16 (rows = out cols)
    const float* __restrict__ br,            // bias / rad
    void* __restrict__ outv)
{
    __shared__ unsigned short As[2][256 * 64];
    __shared__ unsigned short Bs[2][256 * 64];

    const int tid = threadIdx.x;
    const int l = tid & 63, w = tid >> 6;
    const int wm = w >> 2, wn = w & 3;
    const int lrow = l & 15, lhi = l >> 4, lx = l & 7;

    // bijective XCD swizzle; n-OUTER decomposition (B panel L2-resident per XCD)
    const int nwg = gridDim.x * gridDim.y;
    const int b = blockIdx.y * gridDim.x + blockIdx.x;
    const int q8 = nwg >> 3, r8 = nwg & 7;
    const int xcd = b & 7, idx = b >> 3;
    const int wg = (xcd < r8 ? xcd * (q8 + 1) : r8 * (q8 + 1) + (xcd - r8) * q8) + idx;
    const int m0 = (wg % gridDim.y) * 256;
    const int n0 = (wg / gridDim.y) * 256;

    const int NI = (KD >> 6) >> 1;

    const int rr = tid >> 3;                    // 0..63
    const int cc = (tid & 7) ^ (rr & 7);        // inverse-swizzled global chunk

    const unsigned short* gA = A + (size_t)(m0 + rr) * KD + cc * 8;
    const unsigned short* gB = BT + (size_t)(n0 + (rr & 31) + (rr >> 5) * 64) * KD + cc * 8;

    auto stageA = [&](int dbuf, int kt, int half) {
        #pragma unroll
        for (int j = 0; j < 2; j++)
            gload16(gA + (size_t)(j * 128 + half * 64) * KD + kt * 64,
                    &As[dbuf][(size_t)(w * 8 + j * 128 + half * 64) * 64]);
    };
    // B half = nh stripes: rows {0-31,64-95,128-159,192-223} (+32 for half=1)
    auto stageB = [&](int dbuf, int kt, int half) {
        #pragma unroll
        for (int j = 0; j < 2; j++)
            gload16(gB + (size_t)(j * 128 + half * 32) * KD + kt * 64,
                    &Bs[dbuf][(size_t)((w & 3) * 8 + (w >> 2) * 64 + j * 128 + half * 32) * 64]);
    };

    // prologue: tile0 all 4 halves + tile1 lo halves; retire tile0, leave 4
    stageA(0, 0, 0); stageB(0, 0, 0); stageA(0, 0, 1); stageB(0, 0, 1);
    stageA(1, 1, 0); stageB(1, 1, 0);
    asm volatile("s_waitcnt vmcnt(4)" ::: "memory");
    __builtin_amdgcn_s_barrier();

    f32x4 acc[8][4] = {};
    bf16x8 b0[2][2], b1[2][2];

#define LDB(BUF, NH, DST) do { _Pragma("unroll")                              \
    for (int nj = 0; nj < 2; nj++) { _Pragma("unroll")                        \
        for (int ks = 0; ks < 2; ks++) {                                      \
            const int row_ = wn * 64 + (NH) * 32 + nj * 16 + lrow;            \
            const int ch_ = (ks * 4 + lhi) ^ lx;                              \
            DST[nj][ks] = *(const bf16x8*)&Bs[BUF][row_ * 64 + ch_ * 8];      \
        } } } while (0)

// one phase's compute: per mi, read the A-pair then its 8 MFMAs (interleaved)
#define PH(BUF, MH) do { _Pragma("unroll")                                    \
    for (int mi = 0; mi < 4; mi++) {                                          \
        const int row_ = wm * 128 + (MH) * 64 + mi * 16 + lrow;               \
        bf16x8 a0_ = *(const bf16x8*)&As[BUF][row_ * 64 + (lhi ^ lx) * 8];    \
        bf16x8 a1_ = *(const bf16x8*)&As[BUF][row_ * 64 + ((4 + lhi) ^ lx) * 8];\
        __builtin_amdgcn_s_setprio(1);                                        \
        _Pragma("unroll")                                                     \
        for (int nj = 0; nj < 2; nj++) {                                      \
            acc[(MH)*4+mi][nj] = __builtin_amdgcn_mfma_f32_16x16x32_bf16(     \
                a0_, b0[nj][0], acc[(MH)*4+mi][nj], 0, 0, 0);                 \
            acc[(MH)*4+mi][nj] = __builtin_amdgcn_mfma_f32_16x16x32_bf16(     \
                a1_, b0[nj][1], acc[(MH)*4+mi][nj], 0, 0, 0);                 \
            acc[(MH)*4+mi][2+nj] = __builtin_amdgcn_mfma_f32_16x16x32_bf16(   \
                a0_, b1[nj][0], acc[(MH)*4+mi][2+nj], 0, 0, 0);               \
            acc[(MH)*4+mi][2+nj] = __builtin_amdgcn_mfma_f32_16x16x32_bf16(   \
                a1_, b1[nj][1], acc[(MH)*4+mi][2+nj], 0, 0, 0);               \
        }                                                                     \
        __builtin_amdgcn_s_setprio(0);                                        \
    } } while (0)

    for (int t = 0; t < NI; t++) {
        const bool nl = (t + 1 < NI);
        // P1: tile 2t (buf0), MH0
        LDB(0, 0, b0); LDB(0, 1, b1);
        stageA(1, 2 * t + 1, 1); stageB(1, 2 * t + 1, 1);
        PH(0, 0);
        __builtin_amdgcn_s_barrier();
        // P2: tile 2t, MH1 (b0,b1 reused)
        if (nl) { stageA(0, 2 * t + 2, 0); stageB(0, 2 * t + 2, 0); }
        PH(0, 1);
        if (nl) asm volatile("s_waitcnt vmcnt(4)" ::: "memory");
        else    asm volatile("s_waitcnt vmcnt(0)" ::: "memory");
        __builtin_amdgcn_s_barrier();
        // P3: tile 2t+1 (buf1), MH0
        LDB(1, 0, b0); LDB(1, 1, b1);
        if (nl) { stageA(0, 2 * t + 2, 1); stageB(0, 2 * t + 2, 1); }
        PH(1, 0);
        __builtin_amdgcn_s_barrier();
        // P4: tile 2t+1, MH1
        if (nl) { stageA(1, 2 * t + 3, 0); stageB(1, 2 * t + 3, 0); }
        PH(1, 1);
        if (nl) asm volatile("s_waitcnt vmcnt(4)" ::: "memory");
        else    asm volatile("s_waitcnt vmcnt(0)" ::: "memory");
        __builtin_amdgcn_s_barrier();
    }
#undef LDB
#undef PH

    // epilogue — C/D layout: col = lane&15, row = (lane>>4)*4 + reg
    const int cl = l & 15, rh = (l >> 4) * 4;
    float brv[4];
    #pragma unroll
    for (int nj = 0; nj < 4; nj++) brv[nj] = br[n0 + wn * 64 + nj * 16 + cl];
    #pragma unroll
    for (int mi = 0; mi < 8; mi++) {
        #pragma unroll
        for (int r4 = 0; r4 < 4; r4++) {
            const int row = m0 + wm * 128 + mi * 16 + rh + r4;
            if (MODE == 2 && row >= N_NODES) continue;
            #pragma unroll
            for (int nj = 0; nj < 4; nj++) {
                const int col = n0 + wn * 64 + nj * 16 + cl;
                float x = acc[mi][nj][r4];
                if (MODE == 0) {
                    ((unsigned short*)outv)[(size_t)row * KDIM + col] = f2bf(x + brv[nj]);
                } else {
                    x += fabsf(brv[nj]);
                    ((float*)outv)[(size_t)row * (size_t)NB_GOS + col] =
                        1.0f / (1.0f + __expf(-x));
                }
            }
        }
    }
}

// ---------------- fallback 128x128 GEMM (rounds 3/4, unchanged) ----------------

__global__ void init_buckets(int* cnt, int* cursor, int* bucket) {
    int i = blockIdx.x * 256 + threadIdx.x;
    if (i < 8) { cnt[i] = 0; cursor[i] = 0; }
    if (i < CAP2) bucket[i] = -1;
}

__global__ __launch_bounds__(256) void count_etypes(const int* __restrict__ et, int* cnt) {
    __shared__ int lc[N_RELS];
    if (threadIdx.x < N_RELS) lc[threadIdx.x] = 0;
    __syncthreads();
    int e = blockIdx.x * 256 + threadIdx.x;
    if (e < N_EDGES) atomicAdd(&lc[et[e]], 1);
    __syncthreads();
    if (threadIdx.x < N_RELS) atomicAdd(&cnt[threadIdx.x], lc[threadIdx.x]);
}

__global__ void calc_offsets(const int* __restrict__ cnt, int* offs) {
    if (blockIdx.x == 0 && threadIdx.x == 0) {
        int acc = 0;
        offs[0] = 0;
        for (int r = 0; r < N_RELS; r++) {
            acc += ((cnt[r] + BM - 1) / BM) * BM;
            offs[r + 1] = acc;
        }
    }
}

__global__ __launch_bounds__(256) void scatter_edges(const int* __restrict__ et,
                                                     const int* __restrict__ offs,
                                                     int* cursor, int* bucket) {
    __shared__ int lc[N_RELS];
    __shared__ int lbase[N_RELS];
    if (threadIdx.x < N_RELS) lc[threadIdx.x] = 0;
    __syncthreads();
    int e = blockIdx.x * 256 + threadIdx.x;
    int r = 0, my = 0;
    bool valid = (e < N_EDGES);
    if (valid) { r = et[e]; my = atomicAdd(&lc[r], 1); }
    __syncthreads();
    if (threadIdx.x < N_RELS)
        lbase[threadIdx.x] = atomicAdd(&cursor[threadIdx.x], lc[threadIdx.x]);
    __syncthreads();
    if (valid) bucket[offs[r] + lbase[r] + my] = e;
}

template<int MODE>
__global__ __launch_bounds__(256) void mfma_gemm(
    const unsigned short* __restrict__ A,
    const unsigned short* __restrict__ BT,
    const float* __restrict__ br,
    float* __restrict__ out,
    const int* __restrict__ src,
    const int* __restrict__ dst,
    const int* __restrict__ bucket,
    const int* __restrict__ offs,
    int kd)
{
    __shared__ unsigned short As[BM * BK];
    __shared__ unsigned short Bs[BN * BK];
    __shared__ int s_src[BM];
    __shared__ int s_dst[BM];

    const int tid = threadIdx.x;
    const int l = tid & 63;
    const int w = tid >> 6;
    const int wr = w >> 1, wc = w & 1;

    const int nwg = gridDim.x * gridDim.y;
    const int b = blockIdx.y * gridDim.x + blockIdx.x;
    const int cpx = nwg >> 3;
    const int swz = (b & 7) * cpx + (b >> 3);
    const int n0 = (swz / gridDim.y) * BN;
    const int m0 = (swz % gridDim.y) * BM;

    const unsigned short* Bb = BT;
    if (MODE == 1) {
        int rel = -1;
        #pragma unroll
        for (int q = 0; q < N_RELS; q++)
            if (m0 >= offs[q] && m0 < offs[q + 1]) rel = q;
        if (rel < 0) return;
        Bb = BT + (size_t)rel * KDIM * KDIM;
        if (tid < BM) {
            int e = bucket[m0 + tid];
            s_src[tid] = (e >= 0) ? src[e] : -1;
            s_dst[tid] = (e >= 0) ? dst[e] : -1;
        }
        __syncthreads();
    }

    f32x4 acc[4][4] = {};

    const int s0 = tid, s1 = tid + 256;
    const int r0 = s0 >> 2, kc0 = (s0 & 3) * 8;
    const int r1 = s1 >> 2, kc1 = (s1 & 3) * 8;
    unsigned short* ldsA0 = As + (w * 64) * 8;
    unsigned short* ldsA1 = As + (w * 64 + 256) * 8;
    unsigned short* ldsB0 = Bs + (w * 64) * 8;
    unsigned short* ldsB1 = Bs + (w * 64 + 256) * 8;

    size_t arow0, arow1;
    if (MODE == 1) {
        int sr0 = s_src[r0]; arow0 = (sr0 < 0) ? 0 : (size_t)sr0;
        int sr1 = s_src[r1]; arow1 = (sr1 < 0) ? 0 : (size_t)sr1;
    } else {
        arow0 = (size_t)(m0 + r0);
        arow1 = (size_t)(m0 + r1);
    }
    const size_t brow0 = (size_t)(n0 + r0), brow1 = (size_t)(n0 + r1);

    const int fa = (wr * 64 + (l & 15)) * BK + (l >> 4) * 8;
    const int fb = (wc * 64 + (l & 15)) * BK + (l >> 4) * 8;

    for (int k0 = 0; k0 < kd; k0 += BK) {
        gload16(A + arow0 * kd + k0 + kc0, ldsA0);
        gload16(A + arow1 * kd + k0 + kc1, ldsA1);
        gload16(Bb + brow0 * kd + k0 + kc0, ldsB0);
        gload16(Bb + brow1 * kd + k0 + kc1, ldsB1);
        __syncthreads();

        bf16x8 a[4], bfr[4];
        #pragma unroll
        for (int mi = 0; mi < 4; mi++)
            a[mi] = *(const bf16x8*)&As[fa + mi * 16 * BK];
        #pragma unroll
        for (int nj = 0; nj < 4; nj++)
            bfr[nj] = *(const bf16x8*)&Bs[fb + nj * 16 * BK];
        #pragma unroll
        for (int mi = 0; mi < 4; mi++)
            #pragma unroll
            for (int nj = 0; nj < 4; nj++)
                acc[mi][nj] = __builtin_amdgcn_mfma_f32_16x16x32_bf16(a[mi], bfr[nj], acc[mi][nj], 0, 0, 0);
        __syncthreads();
    }

    const int cl = l & 15, rh = (l >> 4) * 4;
    #pragma unroll
    for (int mi = 0; mi < 4; mi++) {
        #pragma unroll
        for (int r4 = 0; r4 < 4; r4++) {
            const int row = wr * 64 + mi * 16 + rh + r4;
            if (MODE == 1) {
                const int d = s_dst[row];
                if (d >= 0) {
                    #pragma unroll
                    for (int nj = 0; nj < 4; nj++) {
                        const int col = n0 + wc * 64 + nj * 16 + cl;
                        atomicAdd(&out[(size_t)d * KDIM + col], acc[mi][nj][r4]);
                    }
                }
            } else if (MODE == 0) {
                #pragma unroll
                for (int nj = 0; nj < 4; nj++) {
                    const int col = n0 + wc * 64 + nj * 16 + cl;
                    out[(size_t)(m0 + row) * KDIM + col] = acc[mi][nj][r4] + br[col];
                }
            } else {
                #pragma unroll
                for (int nj = 0; nj < 4; nj++) {
                    const int col = n0 + wc * 64 + nj * 16 + cl;
                    float x = acc[mi][nj][r4] + fabsf(br[col]);
                    out[(size_t)(m0 + row) * (size_t)NB_GOS + col] = 1.0f / (1.0f + expf(-x));
                }
            }
        }
    }
}

// ---------------- launch ----------------

extern "C" void kernel_launch(void* const* d_in, const int* in_sizes, int n_in,
                              void* d_out, int out_size, void* d_ws, size_t ws_size,
                              hipStream_t stream) {
    const float* feat   = (const float*)d_in[0];
    const int*   src    = (const int*)d_in[1];
    const int*   dst    = (const int*)d_in[2];
    const int*   etypes = (const int*)d_in[3];
    const float* W_rel  = (const float*)d_in[4];
    const float* W_loop = (const float*)d_in[5];
    const float* bias   = (const float*)d_in[6];
    const float* go_emb = (const float*)d_in[7];
    const float* go_rad = (const float*)d_in[8];
    float* out = (float*)d_out;

    // ---- fast-path workspace layout (~323 MB) ----
    const size_t ACAT_B = (size_t)MPAD * KCAT * 2;      // 264,241,152
    const size_t HB_B   = (size_t)MPAD * KDIM * 2;      //  33,030,144 (bf16 h)
    const size_t BTC_B  = (size_t)KDIM * KCAT * 2;      //  16,777,216
    const size_t GOB_B  = (size_t)NB_GOS * KDIM * 2;    //   8,388,608
    const size_t CNT_B  = 16384 * 4;
    const size_t NEED   = ACAT_B + HB_B + BTC_B + GOB_B + 3 * CNT_B + (size_t)N_EDGES * 4;

    if (ws_size >= NEED) {
        char* p = (char*)d_ws;
        unsigned short* Acat  = (unsigned short*)p;  p += ACAT_B;
        unsigned short* hb    = (unsigned short*)p;  p += HB_B;
        unsigned short* BTcat = (unsigned short*)p;  p += BTC_B;
        unsigned short* gob   = (unsigned short*)p;  p += GOB_B;
        int* cnt    = (int*)p;                       p += CNT_B;
        int* cursor = (int*)p;                       p += CNT_B;
        int* offs   = (int*)p;                       p += CNT_B;
        int* se     = (int*)p;

        zero_ints<<<(2 * 16384 + 255) / 256, 256, 0, stream>>>(cnt, 2 * 16384);
        conv_cat<<<(N_NODES * (KDIM / 8) + 255) / 256, 256, 0, stream>>>(feat, Acat);
        conv_bf16<<<(NB_GOS * KDIM / 8 + 255) / 256, 256, 0, stream>>>(go_emb, gob, NB_GOS * KDIM / 8);
        {
            dim3 g(KDIM / 32, KDIM / 32, N_RELS + 1), bb(32, 8);
            transpose_cat<<<g, bb, 0, stream>>>(W_rel, W_loop, BTcat);
        }
        hist_dst<<<(N_EDGES + 255) / 256, 256, 0, stream>>>(dst, cnt);
        scan_offs<<<1, 1024, 0, stream>>>(cnt, offs);
        scatter_dst<<<(N_EDGES + 255) / 256, 256, 0, stream>>>(src, dst, etypes, offs, cursor, se);
        aggregate<<<N_NODES, 256, 0, stream>>>(offs, se, Acat);

        // hb = bf16([feat | agg] @ [W_loop; W_rel]^T + bias)   (K = 8192)
        {
            dim3 g(KDIM / 256, MPAD / 256);    // (4, 63) -> 252 wgs
            gemm256<0, KCAT><<<g, 512, 0, stream>>>(Acat, BTcat, bias, hb);
        }
        // out = sigmoid(hb @ go^T + |rad|)   (K = 1024)
        {
            dim3 g(NB_GOS / 256, MPAD / 256);  // (16, 63) -> 1008 wgs
            gemm256<2, KDIM><<<g, 512, 0, stream>>>(hb, gob, go_rad, out);
        }
        return;
    }

    // ---- fallback: rounds-3/4 path (~124 MB ws) ----
    char* p = (char*)d_ws;
    float* h            = (float*)p;            p += (size_t)N_NODES * KDIM * 4;
    unsigned short* fb  = (unsigned short*)p;   p += (size_t)N_NODES * KDIM * 2;
    unsigned short* wrT = (unsigned short*)p;   p += (size_t)N_RELS * KDIM * KDIM * 2;
    unsigned short* wlT = (unsigned short*)p;   p += (size_t)KDIM * KDIM * 2;
    unsigned short* gob = (unsigned short*)p;   p += (size_t)NB_GOS * KDIM * 2;
    int* cnt    = (int*)p;
    int* cursor = cnt + 8;
    int* offs   = cursor + 8;
    int* bucket = offs + 16;

    conv_bf16<<<(N_NODES * KDIM / 8 + 255) / 256, 256, 0, stream>>>(feat, fb, N_NODES * KDIM / 8);
    conv_bf16<<<(NB_GOS * KDIM / 8 + 255) / 256, 256, 0, stream>>>(go_emb, gob, NB_GOS * KDIM / 8);
    {
        dim3 g(KDIM / 32, KDIM / 32, N_RELS + 1), bb(32, 8);
        transpose_w<<<g, bb, 0, stream>>>(W_rel, W_loop, wrT, wlT);
    }
    init_buckets<<<(CAP2 + 255) / 256, 256, 0, stream>>>(cnt, cursor, bucket);
    count_etypes<<<(N_EDGES + 255) / 256, 256, 0, stream>>>(etypes, cnt);
    calc_offsets<<<1, 64, 0, stream>>>(cnt, offs);
    scatter_edges<<<(N_EDGES + 255) / 256, 256, 0, stream>>>(etypes, offs, cursor, bucket);
    {
        dim3 g(KDIM / BN, N_NODES / BM);
        mfma_gemm<0><<<g, 256, 0, stream>>>(fb, wlT, bias, h, nullptr, nullptr, nullptr, nullptr, KDIM);
    }
    {
        dim3 g(KDIM / BN, NTILE_E);
        mfma_gemm<1><<<g, 256, 0, stream>>>(fb, wrT, nullptr, h, src, dst, bucket, offs, KDIM);
    }
    conv_bf16<<<(N_NODES * KDIM / 8 + 255) / 256, 256, 0, stream>>>(h, fb, N_NODES * KDIM / 8);
    {
        dim3 g(NB_GOS / BN, N_NODES / BM);
        mfma_gemm<2><<<g, 256, 0, stream>>>(fb, gob, go_rad, out, nullptr, nullptr, nullptr, nullptr, KDIM);
    }
}

// Round 13
// 571.210 us; speedup vs baseline: 1.1111x; 1.1111x over previous
//
#include <hip/hip_runtime.h>
#include <math.h>

#define N_NODES 16000
#define N_EDGES 128000
#define KDIM 1024
#define N_RELS 7
#define NB_GOS 4096
#define KCAT (KDIM * (N_RELS + 1))     // 8192: [feat | agg r0..r6]
#define MPAD 16128                     // 126 * 128

#define BM 128
#define BN 128
#define BK 32
#define CAP2 (N_EDGES + N_RELS * BM)   // fallback path
#define NTILE_E (CAP2 / BM)

typedef __attribute__((ext_vector_type(8))) short bf16x8;
typedef __attribute__((ext_vector_type(8))) unsigned short u16x8;
typedef __attribute__((ext_vector_type(4))) float f32x4;

__device__ __forceinline__ unsigned short f2bf(float f) {
    union { float f; unsigned int u; } v; v.f = f;
    unsigned int u = v.u + 0x7FFFu + ((v.u >> 16) & 1u);   // RNE
    return (unsigned short)(u >> 16);
}

__device__ __forceinline__ float bf2f(unsigned short u) {
    union { unsigned int u; float f; } v; v.u = (unsigned int)u << 16;
    return v.f;
}

__device__ __forceinline__ void gload16(const void* g, void* lds) {
    __builtin_amdgcn_global_load_lds(
        (const __attribute__((address_space(1))) unsigned int*)g,
        (__attribute__((address_space(3))) unsigned int*)lds, 16, 0, 0);
}

// ---------------- prep kernels ----------------

__global__ __launch_bounds__(256) void conv_bf16(const float* __restrict__ in,
                                                 unsigned short* __restrict__ out, int n8) {
    int i = blockIdx.x * 256 + threadIdx.x;
    if (i >= n8) return;
    const float4* in4 = (const float4*)in;
    float4 x = in4[2 * i], y = in4[2 * i + 1];
    u16x8 o;
    o[0] = f2bf(x.x); o[1] = f2bf(x.y); o[2] = f2bf(x.z); o[3] = f2bf(x.w);
    o[4] = f2bf(y.x); o[5] = f2bf(y.y); o[6] = f2bf(y.z); o[7] = f2bf(y.w);
    *(u16x8*)&out[(size_t)i * 8] = o;
}

__global__ __launch_bounds__(256) void conv_cat(const float* __restrict__ in,
                                                unsigned short* __restrict__ Acat) {
    int i = blockIdx.x * 256 + threadIdx.x;
    if (i >= N_NODES * (KDIM / 8)) return;
    int n = i >> 7, c8 = (i & 127) * 8;
    const float4* in4 = (const float4*)(in + (size_t)n * KDIM + c8);
    float4 x = in4[0], y = in4[1];
    u16x8 o;
    o[0] = f2bf(x.x); o[1] = f2bf(x.y); o[2] = f2bf(x.z); o[3] = f2bf(x.w);
    o[4] = f2bf(y.x); o[5] = f2bf(y.y); o[6] = f2bf(y.z); o[7] = f2bf(y.w);
    *(u16x8*)&Acat[(size_t)n * KCAT + c8] = o;
}

__global__ void transpose_w(const float* __restrict__ Wrel,
                            const float* __restrict__ Wloop,
                            unsigned short* __restrict__ WrelT,
                            unsigned short* __restrict__ WloopT) {
    __shared__ float t[32][33];
    int z = blockIdx.z;
    const float* src = (z < N_RELS) ? Wrel + (size_t)z * KDIM * KDIM : Wloop;
    unsigned short* dst = (z < N_RELS) ? WrelT + (size_t)z * KDIM * KDIM : WloopT;
    int tx = threadIdx.x, ty = threadIdx.y;
    int x = blockIdx.x * 32 + tx;
    int y0 = blockIdx.y * 32;
    #pragma unroll
    for (int j = 0; j < 4; j++)
        t[ty + 8 * j][tx] = src[(size_t)(y0 + ty + 8 * j) * KDIM + x];
    __syncthreads();
    #pragma unroll
    for (int j = 0; j < 4; j++) {
        int n = blockIdx.x * 32 + ty + 8 * j;
        dst[(size_t)n * KDIM + y0 + tx] = f2bf(t[tx][ty + 8 * j]);
    }
}

__global__ void transpose_cat(const float* __restrict__ Wrel,
                              const float* __restrict__ Wloop,
                              unsigned short* __restrict__ BT) {
    __shared__ float t[32][33];
    int z = blockIdx.z;
    const float* src = (z == 0) ? Wloop : Wrel + (size_t)(z - 1) * KDIM * KDIM;
    int tx = threadIdx.x, ty = threadIdx.y;
    int x = blockIdx.x * 32 + tx;
    int y0 = blockIdx.y * 32;
    #pragma unroll
    for (int j = 0; j < 4; j++)
        t[ty + 8 * j][tx] = src[(size_t)(y0 + ty + 8 * j) * KDIM + x];
    __syncthreads();
    #pragma unroll
    for (int j = 0; j < 4; j++) {
        int o = blockIdx.x * 32 + ty + 8 * j;
        BT[(size_t)o * KCAT + z * KDIM + y0 + tx] = f2bf(t[tx][ty + 8 * j]);
    }
}

// ---------------- dst-sort + aggregation (fast path) ----------------

__global__ void zero_ints(int* p, int n) {
    int i = blockIdx.x * 256 + threadIdx.x;
    if (i < n) p[i] = 0;
}

__global__ void hist_dst(const int* __restrict__ dst, int* cnt) {
    int e = blockIdx.x * 256 + threadIdx.x;
    if (e < N_EDGES) atomicAdd(&cnt[dst[e]], 1);
}

__global__ __launch_bounds__(1024) void scan_offs(const int* __restrict__ cnt,
                                                  int* __restrict__ offs) {
    __shared__ int part[1024];
    int t = threadIdx.x;
    int base = t * 16;
    int local[16];
    int s = 0;
    if (base < N_NODES) {
        #pragma unroll
        for (int j = 0; j < 16; j++) { local[j] = cnt[base + j]; s += local[j]; }
    }
    part[t] = s;
    __syncthreads();
    for (int d = 1; d < 1024; d <<= 1) {
        int v = (t >= d) ? part[t - d] : 0;
        __syncthreads();
        part[t] += v;
        __syncthreads();
    }
    if (base < N_NODES) {
        int ex = (t == 0) ? 0 : part[t - 1];
        #pragma unroll
        for (int j = 0; j < 16; j++) { offs[base + j] = ex; ex += local[j]; }
        if (base + 16 == N_NODES) offs[N_NODES] = ex;
    }
}

__global__ void scatter_dst(const int* __restrict__ src, const int* __restrict__ dst,
                            const int* __restrict__ et, const int* __restrict__ offs,
                            int* cursor, int* __restrict__ se) {
    int e = blockIdx.x * 256 + threadIdx.x;
    if (e < N_EDGES) {
        int d = dst[e];
        int p = atomicAdd(&cursor[d], 1);
        se[offs[d] + p] = (src[e] << 3) | et[e];
    }
}

// per-node aggregation: reads src rows in BF16 from Acat's feat region,
// fp32 accumulate, bf16 store.
__global__ __launch_bounds__(256) void aggregate(const int* __restrict__ offs,
                                                 const int* __restrict__ se,
                                                 unsigned short* __restrict__ Acat) {
    int n = blockIdx.x;
    int t = threadIdx.x;
    int e0 = offs[n], e1 = offs[n + 1];
    float4 a0 = {0,0,0,0}, a1 = a0, a2 = a0, a3 = a0, a4 = a0, a5 = a0, a6 = a0;
    for (int i = e0; i < e1; i++) {
        int v = se[i];                      // wave-uniform
        int s = v >> 3, r = v & 7;
        ushort4 q = *(const ushort4*)&Acat[(size_t)s * KCAT + t * 4];
        float4 x = { bf2f(q.x), bf2f(q.y), bf2f(q.z), bf2f(q.w) };
        #define ADD4(a) { a.x += x.x; a.y += x.y; a.z += x.z; a.w += x.w; }
        switch (r) {
            case 0: ADD4(a0) break; case 1: ADD4(a1) break;
            case 2: ADD4(a2) break; case 3: ADD4(a3) break;
            case 4: ADD4(a4) break; case 5: ADD4(a5) break;
            default: ADD4(a6) break;
        }
        #undef ADD4
    }
    unsigned short* row = Acat + (size_t)n * KCAT + KDIM;
    #define ST4(rr, a) { ushort4 o; o.x = f2bf(a.x); o.y = f2bf(a.y); \
                         o.z = f2bf(a.z); o.w = f2bf(a.w); \
                         *(ushort4*)(row + rr * KDIM + t * 4) = o; }
    ST4(0, a0) ST4(1, a1) ST4(2, a2) ST4(3, a3) ST4(4, a4) ST4(5, a5) ST4(6, a6)
    #undef ST4
}

// ======== 128x256 GEMM, BK=32, 3-buffer rotation, 2 blocks/CU ========
// MODE 0: hb = bf16(A @ BT^T + bias)        MODE 2: out = sigmoid(... + |rad|)
// vs r11/r12: tile halved to 128x256 with BK=32 and LDS cut to 72 KiB
// (3 bufs x (A 8K + B 16K)) so TWO blocks fit per CU (160 KiB). The two
// blocks have independent barriers -> one block's barrier/LDS phases overlap
// the other's MFMA (m114 cross-wave mechanism) — the overlap r5-r12's
// single-block schedules could never get. Same phase count (K/32) and same
// LDS-traffic/FLOP as r11.
// Phase kt: {8 ds_read_b128 (bunched, r11 style); stage tile kt+2 (3 gloads)
// into buf vacated at kt-1 (WAR-clean: last read ended >=1 barrier ago);
// 16 MFMA (setprio); vmcnt(3) retires tile kt+1's 3 loads; s_barrier}.
// Issue->consume = 2 phases (~1400cy > 900cy HBM). Prologue stages t0,t1;
// vmcnt(3) retires t0. Tail: no stage when kt+2>=NT; vmcnt(0) at kt=NT-2.
// Swizzle: LDS chunk c of row r holds global chunk c^(r&3)^((r>>2)&3)
// (inverse-swizzled global source; read slot = lhi^(lrow&3)^((lrow>>2)&3);
// <=2-way banks = free per m136).

template<int MODE, int KD>
__global__ __launch_bounds__(512, 4) void gemm128(
    const unsigned short* __restrict__ A,    // [Mpad][KD] bf16
    const unsigned short* __restrict__ BT,   // [N][KD] bf16 (rows = out cols)
    const float* __restrict__ br,            // bias / rad
    void* __restrict__ outv)
{
    __shared__ unsigned short As[3][128 * 32];
    __shared__ unsigned short Bs[3][256 * 32];

    const int tid = threadIdx.x;
    const int l = tid & 63, w = tid >> 6;
    const int wm = w >> 2, wn = w & 3;          // 2M x 4N waves, 64x64 out each
    const int lrow = l & 15, lhi = l >> 4;
    const int chl = lhi ^ (lrow & 3) ^ ((lrow >> 2) & 3);   // read chunk slot

    // bijective XCD swizzle; m-fast within chunk (B panel L2-resident per XCD)
    const int nwg = gridDim.x * gridDim.y;
    const int b = blockIdx.y * gridDim.x + blockIdx.x;
    const int q8 = nwg >> 3, r8 = nwg & 7;
    const int xcd = b & 7, idx = b >> 3;
    const int wg = (xcd < r8 ? xcd * (q8 + 1) : r8 * (q8 + 1) + (xcd - r8) * q8) + idx;
    const int m0 = (wg % gridDim.y) * 128;
    const int n0 = (wg / gridDim.y) * 256;

    const int NT = KD >> 5;

    const int rr = tid >> 2;                    // 0..127
    const int cc = (tid & 3) ^ (rr & 3) ^ ((rr >> 2) & 3);  // inv-swizzled global chunk

    const unsigned short* gAp = A + (size_t)(m0 + rr) * KD + cc * 8;
    const unsigned short* gBp = BT + (size_t)(n0 + rr) * KD + cc * 8;

    auto stageA = [&](int dbuf, int kt) {       // 1 gload: 128 rows x 32 cols
        gload16(gAp + kt * 32, &As[dbuf][w * 512]);
    };
    auto stageB = [&](int dbuf, int kt) {       // 2 gloads: 256 rows
        gload16(gBp + kt * 32, &Bs[dbuf][w * 512]);
        gload16(gBp + (size_t)128 * KD + kt * 32, &Bs[dbuf][4096 + w * 512]);
    };

    // prologue: stage t0->buf0, t1->buf1 (6 loads); retire t0's 3
    stageA(0, 0); stageB(0, 0);
    stageA(1, 1); stageB(1, 1);
    asm volatile("s_waitcnt vmcnt(3)" ::: "memory");
    __builtin_amdgcn_s_barrier();

    f32x4 acc[4][4] = {};

    int cur = 0;
    for (int kt = 0; kt < NT; kt++) {
        // fragment reads (bunched; compiler pipelines the 8 b128s)
        bf16x8 afr[4], bfr[4];
        #pragma unroll
        for (int mi = 0; mi < 4; mi++)
            afr[mi] = *(const bf16x8*)&As[cur][(wm * 64 + mi * 16 + lrow) * 32 + chl * 8];
        #pragma unroll
        for (int nj = 0; nj < 4; nj++)
            bfr[nj] = *(const bf16x8*)&Bs[cur][(wn * 64 + nj * 16 + lrow) * 32 + chl * 8];

        // stage tile kt+2 into the buffer vacated at phase kt-1
        int st = cur + 2; if (st >= 3) st -= 3;
        if (kt + 2 < NT) { stageA(st, kt + 2); stageB(st, kt + 2); }

        __builtin_amdgcn_s_setprio(1);
        #pragma unroll
        for (int mi = 0; mi < 4; mi++)
            #pragma unroll
            for (int nj = 0; nj < 4; nj++)
                acc[mi][nj] = __builtin_amdgcn_mfma_f32_16x16x32_bf16(
                    afr[mi], bfr[nj], acc[mi][nj], 0, 0, 0);
        __builtin_amdgcn_s_setprio(0);

        if (kt + 2 < NT)      asm volatile("s_waitcnt vmcnt(3)" ::: "memory");
        else if (kt + 1 < NT) asm volatile("s_waitcnt vmcnt(0)" ::: "memory");
        __builtin_amdgcn_s_barrier();
        cur++; if (cur == 3) cur = 0;
    }

    // epilogue — C/D layout: col = lane&15, row = (lane>>4)*4 + reg
    const int cl = l & 15, rh = (l >> 4) * 4;
    float brv[4];
    #pragma unroll
    for (int nj = 0; nj < 4; nj++) brv[nj] = br[n0 + wn * 64 + nj * 16 + cl];
    #pragma unroll
    for (int mi = 0; mi < 4; mi++) {
        #pragma unroll
        for (int r4 = 0; r4 < 4; r4++) {
            const int row = m0 + wm * 64 + mi * 16 + rh + r4;
            if (MODE == 2 && row >= N_NODES) continue;
            #pragma unroll
            for (int nj = 0; nj < 4; nj++) {
                const int col = n0 + wn * 64 + nj * 16 + cl;
                float x = acc[mi][nj][r4];
                if (MODE == 0) {
                    ((unsigned short*)outv)[(size_t)row * KDIM + col] = f2bf(x + brv[nj]);
                } else {
                    x += fabsf(brv[nj]);
                    ((float*)outv)[(size_t)row * (size_t)NB_GOS + col] =
                        1.0f / (1.0f + __expf(-x));
                }
            }
        }
    }
}

// ---------------- fallback 128x128 GEMM (rounds 3/4, unchanged) ----------------

__global__ void init_buckets(int* cnt, int* cursor, int* bucket) {
    int i = blockIdx.x * 256 + threadIdx.x;
    if (i < 8) { cnt[i] = 0; cursor[i] = 0; }
    if (i < CAP2) bucket[i] = -1;
}

__global__ __launch_bounds__(256) void count_etypes(const int* __restrict__ et, int* cnt) {
    __shared__ int lc[N_RELS];
    if (threadIdx.x < N_RELS) lc[threadIdx.x] = 0;
    __syncthreads();
    int e = blockIdx.x * 256 + threadIdx.x;
    if (e < N_EDGES) atomicAdd(&lc[et[e]], 1);
    __syncthreads();
    if (threadIdx.x < N_RELS) atomicAdd(&cnt[threadIdx.x], lc[threadIdx.x]);
}

__global__ void calc_offsets(const int* __restrict__ cnt, int* offs) {
    if (blockIdx.x == 0 && threadIdx.x == 0) {
        int acc = 0;
        offs[0] = 0;
        for (int r = 0; r < N_RELS; r++) {
            acc += ((cnt[r] + BM - 1) / BM) * BM;
            offs[r + 1] = acc;
        }
    }
}

__global__ __launch_bounds__(256) void scatter_edges(const int* __restrict__ et,
                                                     const int* __restrict__ offs,
                                                     int* cursor, int* bucket) {
    __shared__ int lc[N_RELS];
    __shared__ int lbase[N_RELS];
    if (threadIdx.x < N_RELS) lc[threadIdx.x] = 0;
    __syncthreads();
    int e = blockIdx.x * 256 + threadIdx.x;
    int r = 0, my = 0;
    bool valid = (e < N_EDGES);
    if (valid) { r = et[e]; my = atomicAdd(&lc[r], 1); }
    __syncthreads();
    if (threadIdx.x < N_RELS)
        lbase[threadIdx.x] = atomicAdd(&cursor[threadIdx.x], lc[threadIdx.x]);
    __syncthreads();
    if (valid) bucket[offs[r] + lbase[r] + my] = e;
}

template<int MODE>
__global__ __launch_bounds__(256) void mfma_gemm(
    const unsigned short* __restrict__ A,
    const unsigned short* __restrict__ BT,
    const float* __restrict__ br,
    float* __restrict__ out,
    const int* __restrict__ src,
    const int* __restrict__ dst,
    const int* __restrict__ bucket,
    const int* __restrict__ offs,
    int kd)
{
    __shared__ unsigned short As[BM * BK];
    __shared__ unsigned short Bs[BN * BK];
    __shared__ int s_src[BM];
    __shared__ int s_dst[BM];

    const int tid = threadIdx.x;
    const int l = tid & 63;
    const int w = tid >> 6;
    const int wr = w >> 1, wc = w & 1;

    const int nwg = gridDim.x * gridDim.y;
    const int b = blockIdx.y * gridDim.x + blockIdx.x;
    const int cpx = nwg >> 3;
    const int swz = (b & 7) * cpx + (b >> 3);
    const int n0 = (swz / gridDim.y) * BN;
    const int m0 = (swz % gridDim.y) * BM;

    const unsigned short* Bb = BT;
    if (MODE == 1) {
        int rel = -1;
        #pragma unroll
        for (int q = 0; q < N_RELS; q++)
            if (m0 >= offs[q] && m0 < offs[q + 1]) rel = q;
        if (rel < 0) return;
        Bb = BT + (size_t)rel * KDIM * KDIM;
        if (tid < BM) {
            int e = bucket[m0 + tid];
            s_src[tid] = (e >= 0) ? src[e] : -1;
            s_dst[tid] = (e >= 0) ? dst[e] : -1;
        }
        __syncthreads();
    }

    f32x4 acc[4][4] = {};

    const int s0 = tid, s1 = tid + 256;
    const int r0 = s0 >> 2, kc0 = (s0 & 3) * 8;
    const int r1 = s1 >> 2, kc1 = (s1 & 3) * 8;
    unsigned short* ldsA0 = As + (w * 64) * 8;
    unsigned short* ldsA1 = As + (w * 64 + 256) * 8;
    unsigned short* ldsB0 = Bs + (w * 64) * 8;
    unsigned short* ldsB1 = Bs + (w * 64 + 256) * 8;

    size_t arow0, arow1;
    if (MODE == 1) {
        int sr0 = s_src[r0]; arow0 = (sr0 < 0) ? 0 : (size_t)sr0;
        int sr1 = s_src[r1]; arow1 = (sr1 < 0) ? 0 : (size_t)sr1;
    } else {
        arow0 = (size_t)(m0 + r0);
        arow1 = (size_t)(m0 + r1);
    }
    const size_t brow0 = (size_t)(n0 + r0), brow1 = (size_t)(n0 + r1);

    const int fa = (wr * 64 + (l & 15)) * BK + (l >> 4) * 8;
    const int fb = (wc * 64 + (l & 15)) * BK + (l >> 4) * 8;

    for (int k0 = 0; k0 < kd; k0 += BK) {
        gload16(A + arow0 * kd + k0 + kc0, ldsA0);
        gload16(A + arow1 * kd + k0 + kc1, ldsA1);
        gload16(Bb + brow0 * kd + k0 + kc0, ldsB0);
        gload16(Bb + brow1 * kd + k0 + kc1, ldsB1);
        __syncthreads();

        bf16x8 a[4], bfr[4];
        #pragma unroll
        for (int mi = 0; mi < 4; mi++)
            a[mi] = *(const bf16x8*)&As[fa + mi * 16 * BK];
        #pragma unroll
        for (int nj = 0; nj < 4; nj++)
            bfr[nj] = *(const bf16x8*)&Bs[fb + nj * 16 * BK];
        #pragma unroll
        for (int mi = 0; mi < 4; mi++)
            #pragma unroll
            for (int nj = 0; nj < 4; nj++)
                acc[mi][nj] = __builtin_amdgcn_mfma_f32_16x16x32_bf16(a[mi], bfr[nj], acc[mi][nj], 0, 0, 0);
        __syncthreads();
    }

    const int cl = l & 15, rh = (l >> 4) * 4;
    #pragma unroll
    for (int mi = 0; mi < 4; mi++) {
        #pragma unroll
        for (int r4 = 0; r4 < 4; r4++) {
            const int row = wr * 64 + mi * 16 + rh + r4;
            if (MODE == 1) {
                const int d = s_dst[row];
                if (d >= 0) {
                    #pragma unroll
                    for (int nj = 0; nj < 4; nj++) {
                        const int col = n0 + wc * 64 + nj * 16 + cl;
                        atomicAdd(&out[(size_t)d * KDIM + col], acc[mi][nj][r4]);
                    }
                }
            } else if (MODE == 0) {
                #pragma unroll
                for (int nj = 0; nj < 4; nj++) {
                    const int col = n0 + wc * 64 + nj * 16 + cl;
                    out[(size_t)(m0 + row) * KDIM + col] = acc[mi][nj][r4] + br[col];
                }
            } else {
                #pragma unroll
                for (int nj = 0; nj < 4; nj++) {
                    const int col = n0 + wc * 64 + nj * 16 + cl;
                    float x = acc[mi][nj][r4] + fabsf(br[col]);
                    out[(size_t)(m0 + row) * (size_t)NB_GOS + col] = 1.0f / (1.0f + expf(-x));
                }
            }
        }
    }
}

// ---------------- launch ----------------

extern "C" void kernel_launch(void* const* d_in, const int* in_sizes, int n_in,
                              void* d_out, int out_size, void* d_ws, size_t ws_size,
                              hipStream_t stream) {
    const float* feat   = (const float*)d_in[0];
    const int*   src    = (const int*)d_in[1];
    const int*   dst    = (const int*)d_in[2];
    const int*   etypes = (const int*)d_in[3];
    const float* W_rel  = (const float*)d_in[4];
    const float* W_loop = (const float*)d_in[5];
    const float* bias   = (const float*)d_in[6];
    const float* go_emb = (const float*)d_in[7];
    const float* go_rad = (const float*)d_in[8];
    float* out = (float*)d_out;

    // ---- fast-path workspace layout (~323 MB) ----
    const size_t ACAT_B = (size_t)MPAD * KCAT * 2;      // 264,241,152
    const size_t HB_B   = (size_t)MPAD * KDIM * 2;      //  33,030,144 (bf16 h)
    const size_t BTC_B  = (size_t)KDIM * KCAT * 2;      //  16,777,216
    const size_t GOB_B  = (size_t)NB_GOS * KDIM * 2;    //   8,388,608
    const size_t CNT_B  = 16384 * 4;
    const size_t NEED   = ACAT_B + HB_B + BTC_B + GOB_B + 3 * CNT_B + (size_t)N_EDGES * 4;

    if (ws_size >= NEED) {
        char* p = (char*)d_ws;
        unsigned short* Acat  = (unsigned short*)p;  p += ACAT_B;
        unsigned short* hb    = (unsigned short*)p;  p += HB_B;
        unsigned short* BTcat = (unsigned short*)p;  p += BTC_B;
        unsigned short* gob   = (unsigned short*)p;  p += GOB_B;
        int* cnt    = (int*)p;                       p += CNT_B;
        int* cursor = (int*)p;                       p += CNT_B;
        int* offs   = (int*)p;                       p += CNT_B;
        int* se     = (int*)p;

        zero_ints<<<(2 * 16384 + 255) / 256, 256, 0, stream>>>(cnt, 2 * 16384);
        conv_cat<<<(N_NODES * (KDIM / 8) + 255) / 256, 256, 0, stream>>>(feat, Acat);
        conv_bf16<<<(NB_GOS * KDIM / 8 + 255) / 256, 256, 0, stream>>>(go_emb, gob, NB_GOS * KDIM / 8);
        {
            dim3 g(KDIM / 32, KDIM / 32, N_RELS + 1), bb(32, 8);
            transpose_cat<<<g, bb, 0, stream>>>(W_rel, W_loop, BTcat);
        }
        hist_dst<<<(N_EDGES + 255) / 256, 256, 0, stream>>>(dst, cnt);
        scan_offs<<<1, 1024, 0, stream>>>(cnt, offs);
        scatter_dst<<<(N_EDGES + 255) / 256, 256, 0, stream>>>(src, dst, etypes, offs, cursor, se);
        aggregate<<<N_NODES, 256, 0, stream>>>(offs, se, Acat);

        // hb = bf16([feat | agg] @ [W_loop; W_rel]^T + bias)   (K = 8192)
        {
            dim3 g(KDIM / 256, MPAD / 128);    // (4, 126) -> 504 wgs
            gemm128<0, KCAT><<<g, 512, 0, stream>>>(Acat, BTcat, bias, hb);
        }
        // out = sigmoid(hb @ go^T + |rad|)   (K = 1024)
        {
            dim3 g(NB_GOS / 256, MPAD / 128);  // (16, 126) -> 2016 wgs
            gemm128<2, KDIM><<<g, 512, 0, stream>>>(hb, gob, go_rad, out);
        }
        return;
    }

    // ---- fallback: rounds-3/4 path (~124 MB ws) ----
    char* p = (char*)d_ws;
    float* h            = (float*)p;            p += (size_t)N_NODES * KDIM * 4;
    unsigned short* fb  = (unsigned short*)p;   p += (size_t)N_NODES * KDIM * 2;
    unsigned short* wrT = (unsigned short*)p;   p += (size_t)N_RELS * KDIM * KDIM * 2;
    unsigned short* wlT = (unsigned short*)p;   p += (size_t)KDIM * KDIM * 2;
    unsigned short* gob = (unsigned short*)p;   p += (size_t)NB_GOS * KDIM * 2;
    int* cnt    = (int*)p;
    int* cursor = cnt + 8;
    int* offs   = cursor + 8;
    int* bucket = offs + 16;

    conv_bf16<<<(N_NODES * KDIM / 8 + 255) / 256, 256, 0, stream>>>(feat, fb, N_NODES * KDIM / 8);
    conv_bf16<<<(NB_GOS * KDIM / 8 + 255) / 256, 256, 0, stream>>>(go_emb, gob, NB_GOS * KDIM / 8);
    {
        dim3 g(KDIM / 32, KDIM / 32, N_RELS + 1), bb(32, 8);
        transpose_w<<<g, bb, 0, stream>>>(W_rel, W_loop, wrT, wlT);
    }
    init_buckets<<<(CAP2 + 255) / 256, 256, 0, stream>>>(cnt, cursor, bucket);
    count_etypes<<<(N_EDGES + 255) / 256, 256, 0, stream>>>(etypes, cnt);
    calc_offsets<<<1, 64, 0, stream>>>(cnt, offs);
    scatter_edges<<<(N_EDGES + 255) / 256, 256, 0, stream>>>(etypes, offs, cursor, bucket);
    {
        dim3 g(KDIM / BN, N_NODES / BM);
        mfma_gemm<0><<<g, 256, 0, stream>>>(fb, wlT, bias, h, nullptr, nullptr, nullptr, nullptr, KDIM);
    }
    {
        dim3 g(KDIM / BN, NTILE_E);
        mfma_gemm<1><<<g, 256, 0, stream>>>(fb, wrT, nullptr, h, src, dst, bucket, offs, KDIM);
    }
    conv_bf16<<<(N_NODES * KDIM / 8 + 255) / 256, 256, 0, stream>>>(h, fb, N_NODES * KDIM / 8);
    {
        dim3 g(NB_GOS / BN, N_NODES / BM);
        mfma_gemm<2><<<g, 256, 0, stream>>>(fb, gob, go_rad, out, nullptr, nullptr, nullptr, nullptr, KDIM);
    }
}

// Round 14
// 556.441 us; speedup vs baseline: 1.1406x; 1.0265x over previous
//
#include <hip/hip_runtime.h>
#include <math.h>

#define N_NODES 16000
#define N_EDGES 128000
#define KDIM 1024
#define N_RELS 7
#define NB_GOS 4096
#define KCAT (KDIM * (N_RELS + 1))     // 8192: [feat | agg r0..r6]
#define MPAD 16128                     // 63 * 256

#define BM 128
#define BN 128
#define BK 32
#define CAP2 (N_EDGES + N_RELS * BM)   // fallback path
#define NTILE_E (CAP2 / BM)

typedef __attribute__((ext_vector_type(8))) short bf16x8;
typedef __attribute__((ext_vector_type(8))) unsigned short u16x8;
typedef __attribute__((ext_vector_type(4))) float f32x4;

__device__ __forceinline__ unsigned short f2bf(float f) {
    union { float f; unsigned int u; } v; v.f = f;
    unsigned int u = v.u + 0x7FFFu + ((v.u >> 16) & 1u);   // RNE
    return (unsigned short)(u >> 16);
}

__device__ __forceinline__ float bf2f(unsigned short u) {
    union { unsigned int u; float f; } v; v.u = (unsigned int)u << 16;
    return v.f;
}

__device__ __forceinline__ void gload16(const void* g, void* lds) {
    __builtin_amdgcn_global_load_lds(
        (const __attribute__((address_space(1))) unsigned int*)g,
        (__attribute__((address_space(3))) unsigned int*)lds, 16, 0, 0);
}

// ---------------- prep kernels ----------------

__global__ __launch_bounds__(256) void conv_bf16(const float* __restrict__ in,
                                                 unsigned short* __restrict__ out, int n8) {
    int i = blockIdx.x * 256 + threadIdx.x;
    if (i >= n8) return;
    const float4* in4 = (const float4*)in;
    float4 x = in4[2 * i], y = in4[2 * i + 1];
    u16x8 o;
    o[0] = f2bf(x.x); o[1] = f2bf(x.y); o[2] = f2bf(x.z); o[3] = f2bf(x.w);
    o[4] = f2bf(y.x); o[5] = f2bf(y.y); o[6] = f2bf(y.z); o[7] = f2bf(y.w);
    *(u16x8*)&out[(size_t)i * 8] = o;
}

// feat fp32 -> bf16 into Acat cols [0,1024); also zeroes cnt/cursor (folded
// zero_ints dispatch — threads i < nz zero z[i], independent of the conversion)
__global__ __launch_bounds__(256) void conv_cat(const float* __restrict__ in,
                                                unsigned short* __restrict__ Acat,
                                                int* __restrict__ z, int nz) {
    int i = blockIdx.x * 256 + threadIdx.x;
    if (i < nz) z[i] = 0;
    if (i >= N_NODES * (KDIM / 8)) return;
    int n = i >> 7, c8 = (i & 127) * 8;
    const float4* in4 = (const float4*)(in + (size_t)n * KDIM + c8);
    float4 x = in4[0], y = in4[1];
    u16x8 o;
    o[0] = f2bf(x.x); o[1] = f2bf(x.y); o[2] = f2bf(x.z); o[3] = f2bf(x.w);
    o[4] = f2bf(y.x); o[5] = f2bf(y.y); o[6] = f2bf(y.z); o[7] = f2bf(y.w);
    *(u16x8*)&Acat[(size_t)n * KCAT + c8] = o;
}

__global__ void transpose_w(const float* __restrict__ Wrel,
                            const float* __restrict__ Wloop,
                            unsigned short* __restrict__ WrelT,
                            unsigned short* __restrict__ WloopT) {
    __shared__ float t[32][33];
    int z = blockIdx.z;
    const float* src = (z < N_RELS) ? Wrel + (size_t)z * KDIM * KDIM : Wloop;
    unsigned short* dst = (z < N_RELS) ? WrelT + (size_t)z * KDIM * KDIM : WloopT;
    int tx = threadIdx.x, ty = threadIdx.y;
    int x = blockIdx.x * 32 + tx;
    int y0 = blockIdx.y * 32;
    #pragma unroll
    for (int j = 0; j < 4; j++)
        t[ty + 8 * j][tx] = src[(size_t)(y0 + ty + 8 * j) * KDIM + x];
    __syncthreads();
    #pragma unroll
    for (int j = 0; j < 4; j++) {
        int n = blockIdx.x * 32 + ty + 8 * j;
        dst[(size_t)n * KDIM + y0 + tx] = f2bf(t[tx][ty + 8 * j]);
    }
}

__global__ void transpose_cat(const float* __restrict__ Wrel,
                              const float* __restrict__ Wloop,
                              unsigned short* __restrict__ BT) {
    __shared__ float t[32][33];
    int z = blockIdx.z;
    const float* src = (z == 0) ? Wloop : Wrel + (size_t)(z - 1) * KDIM * KDIM;
    int tx = threadIdx.x, ty = threadIdx.y;
    int x = blockIdx.x * 32 + tx;
    int y0 = blockIdx.y * 32;
    #pragma unroll
    for (int j = 0; j < 4; j++)
        t[ty + 8 * j][tx] = src[(size_t)(y0 + ty + 8 * j) * KDIM + x];
    __syncthreads();
    #pragma unroll
    for (int j = 0; j < 4; j++) {
        int o = blockIdx.x * 32 + ty + 8 * j;
        BT[(size_t)o * KCAT + z * KDIM + y0 + tx] = f2bf(t[tx][ty + 8 * j]);
    }
}

// ---------------- dst-sort + aggregation (fast path) ----------------

__global__ void zero_ints(int* p, int n) {
    int i = blockIdx.x * 256 + threadIdx.x;
    if (i < n) p[i] = 0;
}

__global__ void hist_dst(const int* __restrict__ dst, int* cnt) {
    int e = blockIdx.x * 256 + threadIdx.x;
    if (e < N_EDGES) atomicAdd(&cnt[dst[e]], 1);
}

__global__ __launch_bounds__(1024) void scan_offs(const int* __restrict__ cnt,
                                                  int* __restrict__ offs) {
    __shared__ int part[1024];
    int t = threadIdx.x;
    int base = t * 16;
    int local[16];
    int s = 0;
    if (base < N_NODES) {
        #pragma unroll
        for (int j = 0; j < 16; j++) { local[j] = cnt[base + j]; s += local[j]; }
    }
    part[t] = s;
    __syncthreads();
    for (int d = 1; d < 1024; d <<= 1) {
        int v = (t >= d) ? part[t - d] : 0;
        __syncthreads();
        part[t] += v;
        __syncthreads();
    }
    if (base < N_NODES) {
        int ex = (t == 0) ? 0 : part[t - 1];
        #pragma unroll
        for (int j = 0; j < 16; j++) { offs[base + j] = ex; ex += local[j]; }
        if (base + 16 == N_NODES) offs[N_NODES] = ex;
    }
}

__global__ void scatter_dst(const int* __restrict__ src, const int* __restrict__ dst,
                            const int* __restrict__ et, const int* __restrict__ offs,
                            int* cursor, int* __restrict__ se) {
    int e = blockIdx.x * 256 + threadIdx.x;
    if (e < N_EDGES) {
        int d = dst[e];
        int p = atomicAdd(&cursor[d], 1);
        se[offs[d] + p] = (src[e] << 3) | et[e];
    }
}

// per-node aggregation: reads src rows in BF16 from Acat's feat region,
// fp32 accumulate, bf16 store.
__global__ __launch_bounds__(256) void aggregate(const int* __restrict__ offs,
                                                 const int* __restrict__ se,
                                                 unsigned short* __restrict__ Acat) {
    int n = blockIdx.x;
    int t = threadIdx.x;
    int e0 = offs[n], e1 = offs[n + 1];
    float4 a0 = {0,0,0,0}, a1 = a0, a2 = a0, a3 = a0, a4 = a0, a5 = a0, a6 = a0;
    for (int i = e0; i < e1; i++) {
        int v = se[i];                      // wave-uniform
        int s = v >> 3, r = v & 7;
        ushort4 q = *(const ushort4*)&Acat[(size_t)s * KCAT + t * 4];
        float4 x = { bf2f(q.x), bf2f(q.y), bf2f(q.z), bf2f(q.w) };
        #define ADD4(a) { a.x += x.x; a.y += x.y; a.z += x.z; a.w += x.w; }
        switch (r) {
            case 0: ADD4(a0) break; case 1: ADD4(a1) break;
            case 2: ADD4(a2) break; case 3: ADD4(a3) break;
            case 4: ADD4(a4) break; case 5: ADD4(a5) break;
            default: ADD4(a6) break;
        }
        #undef ADD4
    }
    unsigned short* row = Acat + (size_t)n * KCAT + KDIM;
    #define ST4(rr, a) { ushort4 o; o.x = f2bf(a.x); o.y = f2bf(a.y); \
                         o.z = f2bf(a.z); o.w = f2bf(a.w); \
                         *(ushort4*)(row + rr * KDIM + t * 4) = o; }
    ST4(0, a0) ST4(1, a1) ST4(2, a2) ST4(3, a3) ST4(4, a4) ST4(5, a5) ST4(6, a6)
    #undef ST4
}

// ======== 256x256 GEMM, BK=64, 2 K-tiles/iter, 4 fat phases, 1 barrier/phase ==
// (r11 configuration — session best: MODE0 284 us, 0 bank conflicts.)
// MODE 0: hb = bf16(A @ BT^T + bias)        MODE 2: out = sigmoid(... + |rad|)
// Phase = {ds_reads; stage-issues; MFMA(setprio); [vmcnt]; s_barrier}.
// Ledger (per wave, 2 loads per stage call):
//  P1: LDA(0,0) LDB(0,0->b0) LDB(0,1->b1); stage Ahi,Bhi(2t+1)->buf1 | 32 MFMA
//  P2: LDA(0,1); stage Alo,Blo(2t+2)->buf0 | 32 MFMA | vmcnt(4)
//  P3: LDA(1,0) LDB->b0,b1;  stage Ahi,Bhi(2t+2)->buf0 | 32 MFMA
//  P4: LDA(1,1); stage Alo,Blo(2t+3)->buf1 | 32 MFMA | vmcnt(4)

template<int MODE, int KD>
__global__ __launch_bounds__(512, 2) void gemm256(
    const unsigned short* __restrict__ A,    // [Mpad][KD] bf16
    const unsigned short* __restrict__ BT,   // [N][KD] bf16 (rows = out cols)
    const float* __restrict__ br,            // bias / rad
    void* __restrict__ outv)
{
    __shared__ unsigned short As[2][256 * 64];
    __shared__ unsigned short Bs[2][256 * 64];

    const int tid = threadIdx.x;
    const int l = tid & 63, w = tid >> 6;
    const int wm = w >> 2, wn = w & 3;
    const int lrow = l & 15, lhi = l >> 4, lx = l & 7;

    // bijective XCD swizzle; n-OUTER decomposition (B panel L2-resident per XCD)
    const int nwg = gridDim.x * gridDim.y;
    const int b = blockIdx.y * gridDim.x + blockIdx.x;
    const int q8 = nwg >> 3, r8 = nwg & 7;
    const int xcd = b & 7, idx = b >> 3;
    const int wg = (xcd < r8 ? xcd * (q8 + 1) : r8 * (q8 + 1) + (xcd - r8) * q8) + idx;
    const int m0 = (wg % gridDim.y) * 256;
    const int n0 = (wg / gridDim.y) * 256;

    const int NI = (KD >> 6) >> 1;

    const int rr = tid >> 3;                    // 0..63
    const int cc = (tid & 7) ^ (rr & 7);        // inverse-swizzled global chunk

    const unsigned short* gA = A + (size_t)(m0 + rr) * KD + cc * 8;
    const unsigned short* gB = BT + (size_t)(n0 + (rr & 31) + (rr >> 5) * 64) * KD + cc * 8;

    auto stageA = [&](int dbuf, int kt, int half) {
        #pragma unroll
        for (int j = 0; j < 2; j++)
            gload16(gA + (size_t)(j * 128 + half * 64) * KD + kt * 64,
                    &As[dbuf][(size_t)(w * 8 + j * 128 + half * 64) * 64]);
    };
    // B half = nh stripes: rows {0-31,64-95,128-159,192-223} (+32 for half=1)
    auto stageB = [&](int dbuf, int kt, int half) {
        #pragma unroll
        for (int j = 0; j < 2; j++)
            gload16(gB + (size_t)(j * 128 + half * 32) * KD + kt * 64,
                    &Bs[dbuf][(size_t)((w & 3) * 8 + (w >> 2) * 64 + j * 128 + half * 32) * 64]);
    };

    // prologue: tile0 all 4 halves + tile1 lo halves; retire tile0, leave 4
    stageA(0, 0, 0); stageB(0, 0, 0); stageA(0, 0, 1); stageB(0, 0, 1);
    stageA(1, 1, 0); stageB(1, 1, 0);
    asm volatile("s_waitcnt vmcnt(4)" ::: "memory");
    __builtin_amdgcn_s_barrier();

    f32x4 acc[8][4] = {};
    bf16x8 afr[4][2], b0[2][2], b1[2][2];

#define LDA(BUF, MH) do { _Pragma("unroll")                                   \
    for (int mi = 0; mi < 4; mi++) { _Pragma("unroll")                        \
        for (int ks = 0; ks < 2; ks++) {                                      \
            const int row_ = wm * 128 + (MH) * 64 + mi * 16 + lrow;           \
            const int ch_ = (ks * 4 + lhi) ^ lx;                              \
            afr[mi][ks] = *(const bf16x8*)&As[BUF][row_ * 64 + ch_ * 8];      \
        } } } while (0)

#define LDB(BUF, NH, DST) do { _Pragma("unroll")                              \
    for (int nj = 0; nj < 2; nj++) { _Pragma("unroll")                        \
        for (int ks = 0; ks < 2; ks++) {                                      \
            const int row_ = wn * 64 + (NH) * 32 + nj * 16 + lrow;            \
            const int ch_ = (ks * 4 + lhi) ^ lx;                              \
            DST[nj][ks] = *(const bf16x8*)&Bs[BUF][row_ * 64 + ch_ * 8];      \
        } } } while (0)

// one fat phase's MFMA cluster: 32 MFMA (MH x both NH quadrants), no barrier
#define MM2(MH) do {                                                          \
    __builtin_amdgcn_s_setprio(1);                                            \
    _Pragma("unroll")                                                         \
    for (int mi = 0; mi < 4; mi++) { _Pragma("unroll")                        \
        for (int nj = 0; nj < 2; nj++) { _Pragma("unroll")                    \
            for (int ks = 0; ks < 2; ks++) {                                  \
                acc[(MH)*4+mi][nj] = __builtin_amdgcn_mfma_f32_16x16x32_bf16( \
                    afr[mi][ks], b0[nj][ks], acc[(MH)*4+mi][nj], 0, 0, 0);    \
                acc[(MH)*4+mi][2+nj] = __builtin_amdgcn_mfma_f32_16x16x32_bf16( \
                    afr[mi][ks], b1[nj][ks], acc[(MH)*4+mi][2+nj], 0, 0, 0);  \
        } } }                                                                 \
    __builtin_amdgcn_s_setprio(0); } while (0)

    for (int t = 0; t < NI; t++) {
        const bool nl = (t + 1 < NI);
        // P1: tile 2t (buf0), MH0 x {NH0,NH1}
        LDA(0, 0); LDB(0, 0, b0); LDB(0, 1, b1);
        stageA(1, 2 * t + 1, 1); stageB(1, 2 * t + 1, 1);
        MM2(0);
        __builtin_amdgcn_s_barrier();
        // P2: tile 2t, MH1 (b0,b1 reused)
        LDA(0, 1);
        if (nl) { stageA(0, 2 * t + 2, 0); stageB(0, 2 * t + 2, 0); }
        MM2(1);
        if (nl) asm volatile("s_waitcnt vmcnt(4)" ::: "memory");
        else    asm volatile("s_waitcnt vmcnt(0)" ::: "memory");
        __builtin_amdgcn_s_barrier();
        // P3: tile 2t+1 (buf1), MH0
        LDA(1, 0); LDB(1, 0, b0); LDB(1, 1, b1);
        if (nl) { stageA(0, 2 * t + 2, 1); stageB(0, 2 * t + 2, 1); }
        MM2(0);
        __builtin_amdgcn_s_barrier();
        // P4: tile 2t+1, MH1
        LDA(1, 1);
        if (nl) { stageA(1, 2 * t + 3, 0); stageB(1, 2 * t + 3, 0); }
        MM2(1);
        if (nl) asm volatile("s_waitcnt vmcnt(4)" ::: "memory");
        else    asm volatile("s_waitcnt vmcnt(0)" ::: "memory");
        __builtin_amdgcn_s_barrier();
    }
#undef LDA
#undef LDB
#undef MM2

    // epilogue — C/D layout: col = lane&15, row = (lane>>4)*4 + reg
    const int cl = l & 15, rh = (l >> 4) * 4;
    float brv[4];
    #pragma unroll
    for (int nj = 0; nj < 4; nj++) brv[nj] = br[n0 + wn * 64 + nj * 16 + cl];
    #pragma unroll
    for (int mi = 0; mi < 8; mi++) {
        #pragma unroll
        for (int r4 = 0; r4 < 4; r4++) {
            const int row = m0 + wm * 128 + mi * 16 + rh + r4;
            if (MODE == 2 && row >= N_NODES) continue;
            #pragma unroll
            for (int nj = 0; nj < 4; nj++) {
                const int col = n0 + wn * 64 + nj * 16 + cl;
                float x = acc[mi][nj][r4];
                if (MODE == 0) {
                    ((unsigned short*)outv)[(size_t)row * KDIM + col] = f2bf(x + brv[nj]);
                } else {
                    x += fabsf(brv[nj]);
                    ((float*)outv)[(size_t)row * (size_t)NB_GOS + col] =
                        1.0f / (1.0f + __expf(-x));
                }
            }
        }
    }
}

// ---------------- fallback 128x128 GEMM (rounds 3/4, unchanged) ----------------

__global__ void init_buckets(int* cnt, int* cursor, int* bucket) {
    int i = blockIdx.x * 256 + threadIdx.x;
    if (i < 8) { cnt[i] = 0; cursor[i] = 0; }
    if (i < CAP2) bucket[i] = -1;
}

__global__ __launch_bounds__(256) void count_etypes(const int* __restrict__ et, int* cnt) {
    __shared__ int lc[N_RELS];
    if (threadIdx.x < N_RELS) lc[threadIdx.x] = 0;
    __syncthreads();
    int e = blockIdx.x * 256 + threadIdx.x;
    if (e < N_EDGES) atomicAdd(&lc[et[e]], 1);
    __syncthreads();
    if (threadIdx.x < N_RELS) atomicAdd(&cnt[threadIdx.x], lc[threadIdx.x]);
}

__global__ void calc_offsets(const int* __restrict__ cnt, int* offs) {
    if (blockIdx.x == 0 && threadIdx.x == 0) {
        int acc = 0;
        offs[0] = 0;
        for (int r = 0; r < N_RELS; r++) {
            acc += ((cnt[r] + BM - 1) / BM) * BM;
            offs[r + 1] = acc;
        }
    }
}

__global__ __launch_bounds__(256) void scatter_edges(const int* __restrict__ et,
                                                     const int* __restrict__ offs,
                                                     int* cursor, int* bucket) {
    __shared__ int lc[N_RELS];
    __shared__ int lbase[N_RELS];
    if (threadIdx.x < N_RELS) lc[threadIdx.x] = 0;
    __syncthreads();
    int e = blockIdx.x * 256 + threadIdx.x;
    int r = 0, my = 0;
    bool valid = (e < N_EDGES);
    if (valid) { r = et[e]; my = atomicAdd(&lc[r], 1); }
    __syncthreads();
    if (threadIdx.x < N_RELS)
        lbase[threadIdx.x] = atomicAdd(&cursor[threadIdx.x], lc[threadIdx.x]);
    __syncthreads();
    if (valid) bucket[offs[r] + lbase[r] + my] = e;
}

template<int MODE>
__global__ __launch_bounds__(256) void mfma_gemm(
    const unsigned short* __restrict__ A,
    const unsigned short* __restrict__ BT,
    const float* __restrict__ br,
    float* __restrict__ out,
    const int* __restrict__ src,
    const int* __restrict__ dst,
    const int* __restrict__ bucket,
    const int* __restrict__ offs,
    int kd)
{
    __shared__ unsigned short As[BM * BK];
    __shared__ unsigned short Bs[BN * BK];
    __shared__ int s_src[BM];
    __shared__ int s_dst[BM];

    const int tid = threadIdx.x;
    const int l = tid & 63;
    const int w = tid >> 6;
    const int wr = w >> 1, wc = w & 1;

    const int nwg = gridDim.x * gridDim.y;
    const int b = blockIdx.y * gridDim.x + blockIdx.x;
    const int cpx = nwg >> 3;
    const int swz = (b & 7) * cpx + (b >> 3);
    const int n0 = (swz / gridDim.y) * BN;
    const int m0 = (swz % gridDim.y) * BM;

    const unsigned short* Bb = BT;
    if (MODE == 1) {
        int rel = -1;
        #pragma unroll
        for (int q = 0; q < N_RELS; q++)
            if (m0 >= offs[q] && m0 < offs[q + 1]) rel = q;
        if (rel < 0) return;
        Bb = BT + (size_t)rel * KDIM * KDIM;
        if (tid < BM) {
            int e = bucket[m0 + tid];
            s_src[tid] = (e >= 0) ? src[e] : -1;
            s_dst[tid] = (e >= 0) ? dst[e] : -1;
        }
        __syncthreads();
    }

    f32x4 acc[4][4] = {};

    const int s0 = tid, s1 = tid + 256;
    const int r0 = s0 >> 2, kc0 = (s0 & 3) * 8;
    const int r1 = s1 >> 2, kc1 = (s1 & 3) * 8;
    unsigned short* ldsA0 = As + (w * 64) * 8;
    unsigned short* ldsA1 = As + (w * 64 + 256) * 8;
    unsigned short* ldsB0 = Bs + (w * 64) * 8;
    unsigned short* ldsB1 = Bs + (w * 64 + 256) * 8;

    size_t arow0, arow1;
    if (MODE == 1) {
        int sr0 = s_src[r0]; arow0 = (sr0 < 0) ? 0 : (size_t)sr0;
        int sr1 = s_src[r1]; arow1 = (sr1 < 0) ? 0 : (size_t)sr1;
    } else {
        arow0 = (size_t)(m0 + r0);
        arow1 = (size_t)(m0 + r1);
    }
    const size_t brow0 = (size_t)(n0 + r0), brow1 = (size_t)(n0 + r1);

    const int fa = (wr * 64 + (l & 15)) * BK + (l >> 4) * 8;
    const int fb = (wc * 64 + (l & 15)) * BK + (l >> 4) * 8;

    for (int k0 = 0; k0 < kd; k0 += BK) {
        gload16(A + arow0 * kd + k0 + kc0, ldsA0);
        gload16(A + arow1 * kd + k0 + kc1, ldsA1);
        gload16(Bb + brow0 * kd + k0 + kc0, ldsB0);
        gload16(Bb + brow1 * kd + k0 + kc1, ldsB1);
        __syncthreads();

        bf16x8 a[4], bfr[4];
        #pragma unroll
        for (int mi = 0; mi < 4; mi++)
            a[mi] = *(const bf16x8*)&As[fa + mi * 16 * BK];
        #pragma unroll
        for (int nj = 0; nj < 4; nj++)
            bfr[nj] = *(const bf16x8*)&Bs[fb + nj * 16 * BK];
        #pragma unroll
        for (int mi = 0; mi < 4; mi++)
            #pragma unroll
            for (int nj = 0; nj < 4; nj++)
                acc[mi][nj] = __builtin_amdgcn_mfma_f32_16x16x32_bf16(a[mi], bfr[nj], acc[mi][nj], 0, 0, 0);
        __syncthreads();
    }

    const int cl = l & 15, rh = (l >> 4) * 4;
    #pragma unroll
    for (int mi = 0; mi < 4; mi++) {
        #pragma unroll
        for (int r4 = 0; r4 < 4; r4++) {
            const int row = wr * 64 + mi * 16 + rh + r4;
            if (MODE == 1) {
                const int d = s_dst[row];
                if (d >= 0) {
                    #pragma unroll
                    for (int nj = 0; nj < 4; nj++) {
                        const int col = n0 + wc * 64 + nj * 16 + cl;
                        atomicAdd(&out[(size_t)d * KDIM + col], acc[mi][nj][r4]);
                    }
                }
            } else if (MODE == 0) {
                #pragma unroll
                for (int nj = 0; nj < 4; nj++) {
                    const int col = n0 + wc * 64 + nj * 16 + cl;
                    out[(size_t)(m0 + row) * KDIM + col] = acc[mi][nj][r4] + br[col];
                }
            } else {
                #pragma unroll
                for (int nj = 0; nj < 4; nj++) {
                    const int col = n0 + wc * 64 + nj * 16 + cl;
                    float x = acc[mi][nj][r4] + fabsf(br[col]);
                    out[(size_t)(m0 + row) * (size_t)NB_GOS + col] = 1.0f / (1.0f + expf(-x));
                }
            }
        }
    }
}

// ---------------- launch ----------------

extern "C" void kernel_launch(void* const* d_in, const int* in_sizes, int n_in,
                              void* d_out, int out_size, void* d_ws, size_t ws_size,
                              hipStream_t stream) {
    const float* feat   = (const float*)d_in[0];
    const int*   src    = (const int*)d_in[1];
    const int*   dst    = (const int*)d_in[2];
    const int*   etypes = (const int*)d_in[3];
    const float* W_rel  = (const float*)d_in[4];
    const float* W_loop = (const float*)d_in[5];
    const float* bias   = (const float*)d_in[6];
    const float* go_emb = (const float*)d_in[7];
    const float* go_rad = (const float*)d_in[8];
    float* out = (float*)d_out;

    // ---- fast-path workspace layout (~323 MB) ----
    const size_t ACAT_B = (size_t)MPAD * KCAT * 2;      // 264,241,152
    const size_t HB_B   = (size_t)MPAD * KDIM * 2;      //  33,030,144 (bf16 h)
    const size_t BTC_B  = (size_t)KDIM * KCAT * 2;      //  16,777,216
    const size_t GOB_B  = (size_t)NB_GOS * KDIM * 2;    //   8,388,608
    const size_t CNT_B  = 16384 * 4;
    const size_t NEED   = ACAT_B + HB_B + BTC_B + GOB_B + 3 * CNT_B + (size_t)N_EDGES * 4;

    if (ws_size >= NEED) {
        char* p = (char*)d_ws;
        unsigned short* Acat  = (unsigned short*)p;  p += ACAT_B;
        unsigned short* hb    = (unsigned short*)p;  p += HB_B;
        unsigned short* BTcat = (unsigned short*)p;  p += BTC_B;
        unsigned short* gob   = (unsigned short*)p;  p += GOB_B;
        int* cnt    = (int*)p;                       p += CNT_B;
        int* cursor = (int*)p;                       p += CNT_B;
        int* offs   = (int*)p;                       p += CNT_B;
        int* se     = (int*)p;

        // conv_cat also zeroes cnt+cursor (folded zero_ints)
        conv_cat<<<(N_NODES * (KDIM / 8) + 255) / 256, 256, 0, stream>>>(feat, Acat, cnt, 2 * 16384);
        conv_bf16<<<(NB_GOS * KDIM / 8 + 255) / 256, 256, 0, stream>>>(go_emb, gob, NB_GOS * KDIM / 8);
        {
            dim3 g(KDIM / 32, KDIM / 32, N_RELS + 1), bb(32, 8);
            transpose_cat<<<g, bb, 0, stream>>>(W_rel, W_loop, BTcat);
        }
        hist_dst<<<(N_EDGES + 255) / 256, 256, 0, stream>>>(dst, cnt);
        scan_offs<<<1, 1024, 0, stream>>>(cnt, offs);
        scatter_dst<<<(N_EDGES + 255) / 256, 256, 0, stream>>>(src, dst, etypes, offs, cursor, se);
        aggregate<<<N_NODES, 256, 0, stream>>>(offs, se, Acat);

        // hb = bf16([feat | agg] @ [W_loop; W_rel]^T + bias)   (K = 8192)
        {
            dim3 g(KDIM / 256, MPAD / 256);    // (4, 63) -> 252 wgs
            gemm256<0, KCAT><<<g, 512, 0, stream>>>(Acat, BTcat, bias, hb);
        }
        // out = sigmoid(hb @ go^T + |rad|)   (K = 1024)
        {
            dim3 g(NB_GOS / 256, MPAD / 256);  // (16, 63) -> 1008 wgs
            gemm256<2, KDIM><<<g, 512, 0, stream>>>(hb, gob, go_rad, out);
        }
        return;
    }

    // ---- fallback: rounds-3/4 path (~124 MB ws) ----
    char* p = (char*)d_ws;
    float* h            = (float*)p;            p += (size_t)N_NODES * KDIM * 4;
    unsigned short* fb  = (unsigned short*)p;   p += (size_t)N_NODES * KDIM * 2;
    unsigned short* wrT = (unsigned short*)p;   p += (size_t)N_RELS * KDIM * KDIM * 2;
    unsigned short* wlT = (unsigned short*)p;   p += (size_t)KDIM * KDIM * 2;
    unsigned short* gob = (unsigned short*)p;   p += (size_t)NB_GOS * KDIM * 2;
    int* cnt    = (int*)p;
    int* cursor = cnt + 8;
    int* offs   = cursor + 8;
    int* bucket = offs + 16;

    conv_bf16<<<(N_NODES * KDIM / 8 + 255) / 256, 256, 0, stream>>>(feat, fb, N_NODES * KDIM / 8);
    conv_bf16<<<(NB_GOS * KDIM / 8 + 255) / 256, 256, 0, stream>>>(go_emb, gob, NB_GOS * KDIM / 8);
    {
        dim3 g(KDIM / 32, KDIM / 32, N_RELS + 1), bb(32, 8);
        transpose_w<<<g, bb, 0, stream>>>(W_rel, W_loop, wrT, wlT);
    }
    init_buckets<<<(CAP2 + 255) / 256, 256, 0, stream>>>(cnt, cursor, bucket);
    count_etypes<<<(N_EDGES + 255) / 256, 256, 0, stream>>>(etypes, cnt);
    calc_offsets<<<1, 64, 0, stream>>>(cnt, offs);
    scatter_edges<<<(N_EDGES + 255) / 256, 256, 0, stream>>>(etypes, offs, cursor, bucket);
    {
        dim3 g(KDIM / BN, N_NODES / BM);
        mfma_gemm<0><<<g, 256, 0, stream>>>(fb, wlT, bias, h, nullptr, nullptr, nullptr, nullptr, KDIM);
    }
    {
        dim3 g(KDIM / BN, NTILE_E);
        mfma_gemm<1><<<g, 256, 0, stream>>>(fb, wrT, nullptr, h, src, dst, bucket, offs, KDIM);
    }
    conv_bf16<<<(N_NODES * KDIM / 8 + 255) / 256, 256, 0, stream>>>(h, fb, N_NODES * KDIM / 8);
    {
        dim3 g(NB_GOS / BN, N_NODES / BM);
        mfma_gemm<2><<<g, 256, 0, stream>>>(fb, gob, go_rad, out, nullptr, nullptr, nullptr, nullptr, KDIM);
    }
}